// Round 10
// baseline (15.533 us; speedup 1.0000x reference)
//
#include <hip/hip_runtime.h>
#include <hip/hip_bf16.h>

// Constants from the reference
#define E_DIM 16
#define H_DIM 8
#define F_DIM 48
#define L_IN 384
#define L_OUT 384
#define SZ_B 4

#define NCHUNK 8            // l-chunks per bh (48 rows each)
#define ROWS_PER_BLOCK 48
#define ROWS_PER_WAVE 6
#define TSTRIDE 20          // padded table row stride (floats)

typedef float f32x4 __attribute__((ext_vector_type(4)));

// Kernel A: per row (bh,l) compute 48 time-dots + 8 voice-dots; lane k's
// result IS element k of the row record -> one coalesced 256B wave-store.
// Row record Tv[bh*384+l][64] = [T0..47, V0..7, V0..7(dup)].
// No LDS scratch, no fences, no cross-lane traffic.
__global__ __launch_bounds__(512)
void bsa_dots_kernel(const float* __restrict__ q,
                     const float* __restrict__ r_voice,
                     const float* __restrict__ e_past,
                     const float* __restrict__ e_future,
                     float* __restrict__ tv_ws) {
    const int chunk = blockIdx.x;   // [0, 8)
    const int bh    = blockIdx.y;   // [0, 32)
    const int h     = bh & (H_DIM - 1);
    const int t     = threadIdx.x;  // [0, 512)
    const int w     = t >> 6;
    const int lane  = t & 63;

    // Table rows (stride 20): 0..47 past[diff], 48..95 future[diff], 96..159 voice
    __shared__ __attribute__((aligned(16))) float tabs[160 * TSTRIDE];        // 12.8 KB
    __shared__ __attribute__((aligned(16))) float qs[ROWS_PER_BLOCK * E_DIM]; // 3 KB

    // Stage transposed tables (this block's h-plane). i = f*16+d; src = i*8+h.
    for (int i = t; i < F_DIM * E_DIM; i += 512) {
        const int f = i >> 4, d = i & 15;
        tabs[f * TSTRIDE + d]           = e_past [(size_t)i * H_DIM + h];
        tabs[(F_DIM + f) * TSTRIDE + d] = e_future[(size_t)i * H_DIM + h];
    }
    for (int i = t; i < 64 * E_DIM; i += 512) {
        const int r = i >> 4, d = i & 15;
        tabs[(96 + r) * TSTRIDE + d] = r_voice[(size_t)i * H_DIM + h];
    }
    // Stage this block's 48 q-rows (contiguous, coalesced)
    for (int i = t; i < ROWS_PER_BLOCK * E_DIM; i += 512)
        qs[i] = q[((size_t)bh * L_IN + chunk * ROWS_PER_BLOCK) * E_DIM + i];
    __syncthreads();

    #pragma unroll
    for (int j = 0; j < ROWS_PER_WAVE; ++j) {
        const int lrow = w * ROWS_PER_WAVE + j;     // [0, 48)
        const int l    = chunk * ROWS_PER_BLOCK + lrow;
        const int fi   = l >> 3;
        const int vi   = l & 7;
        int r;
        if (lane < 48) {
            r = (lane <= fi) ? (fi - lane) : (F_DIM + lane - fi);
        } else {
            r = 96 + vi * 8 + ((lane - 48) & 7);    // lanes 56..63 dup V
        }
        const f32x4* qv = (const f32x4*)&qs[lrow * E_DIM];   // broadcast reads
        const f32x4* tv = (const f32x4*)&tabs[r * TSTRIDE];
        f32x4 acc = qv[0] * tv[0] + qv[1] * tv[1] + qv[2] * tv[2] + qv[3] * tv[3];
        const float s = acc.x + acc.y + acc.z + acc.w;
        tv_ws[((size_t)bh * L_IN + l) * 64 + lane] = s;      // coalesced 256B
    }
}

// Kernel B: pure streaming expansion, one float4 per thread (fill-kernel shape).
// out[row][4*jj .. 4*jj+3] = Tv[row][jj>>1] + Tv[row][48+4*(jj&1) ..]
__global__ __launch_bounds__(256)
void bsa_expand_kernel(const float* __restrict__ tv_ws,
                       float* __restrict__ out) {
    const int g   = blockIdx.x * 256 + threadIdx.x;  // [0, 1179648)
    const int row = g / 96;
    const int jj  = g - row * 96;
    const float* base = tv_ws + (size_t)row * 64;
    const float tval = base[jj >> 1];
    const f32x4 vv = *(const f32x4*)&base[48 + 4 * (jj & 1)];
    f32x4 o;
    o.x = tval + vv.x; o.y = tval + vv.y;
    o.z = tval + vv.z; o.w = tval + vv.w;
    *(f32x4*)(out + (size_t)4 * g) = o;
}

extern "C" void kernel_launch(void* const* d_in, const int* in_sizes, int n_in,
                              void* d_out, int out_size, void* d_ws, size_t ws_size,
                              hipStream_t stream) {
    const float* q        = (const float*)d_in[0];
    // d_in[1] = flipped_masks (unused)
    const float* r_voice  = (const float*)d_in[2];
    const float* e_past   = (const float*)d_in[3];
    const float* e_future = (const float*)d_in[4];
    float* tv_ws = (float*)d_ws;     // 32*384*64 floats = 3 MB
    float* out   = (float*)d_out;

    bsa_dots_kernel<<<dim3(NCHUNK, SZ_B * H_DIM), dim3(512), 0, stream>>>(
        q, r_voice, e_past, e_future, tv_ws);

    const int total_vec4 = SZ_B * H_DIM * L_IN * (L_OUT / 4);  // 1179648
    bsa_expand_kernel<<<dim3(total_vec4 / 256), dim3(256), 0, stream>>>(tv_ws, out);
}

// Round 11
// 11.595 us; speedup vs baseline: 1.3397x; 1.3397x over previous
//
#include <hip/hip_runtime.h>
#include <hip/hip_bf16.h>

// Constants from the reference
#define E_DIM 16
#define H_DIM 8
#define F_DIM 48
#define L_IN 384
#define L_OUT 384
#define SZ_B 4

#define NCHUNK 16           // l-chunks per bh (24 rows each)  [R6 had 8 x 48]
#define ROWS_PER_BLOCK 24
#define FI_PER 3            // rows per wave
#define TSTRIDE 20          // padded table row stride (floats): 80 B, 16B-aligned b128 rows

typedef float f32x4 __attribute__((ext_vector_type(4)));

// EXACT R6 kernel structure (10.67 us: per-row fence, NT stores, LDS q),
// single variable changed: 2 blocks/CU instead of 1 (grid 16x32, 24 rows/blk)
// so staging/dots/stores of co-resident blocks overlap within a CU.
__global__ __launch_bounds__(512)
void bsa_fused_kernel(const float* __restrict__ q,
                      const float* __restrict__ r_voice,
                      const float* __restrict__ e_past,
                      const float* __restrict__ e_future,
                      float* __restrict__ out) {
    const int chunk = blockIdx.x;   // [0, 16)
    const int bh    = blockIdx.y;   // [0, 32)
    const int h     = bh & (H_DIM - 1);
    const int t     = threadIdx.x;  // [0, 512)
    const int w     = t >> 6;
    const int lane  = t & 63;

    // Table rows (stride TSTRIDE): 0..47 past[diff], 48..95 future[diff], 96..159 voice
    __shared__ __attribute__((aligned(16))) float tabs[160 * TSTRIDE];        // 12.8 KB
    __shared__ __attribute__((aligned(16))) float qs[ROWS_PER_BLOCK * E_DIM]; // 1.5 KB
    __shared__ __attribute__((aligned(16))) float scratch[8 * 64];            // per-wave row results

    // Stage transposed tables (one h-plane). i = f*16+d; flat src = i*8+h.
    for (int i = t; i < F_DIM * E_DIM; i += 512) {
        const int f = i >> 4, d = i & 15;
        tabs[f * TSTRIDE + d]           = e_past [(size_t)i * H_DIM + h];
        tabs[(F_DIM + f) * TSTRIDE + d] = e_future[(size_t)i * H_DIM + h];
    }
    for (int i = t; i < 64 * E_DIM; i += 512) {
        const int r = i >> 4, d = i & 15;
        tabs[(96 + r) * TSTRIDE + d] = r_voice[(size_t)i * H_DIM + h];
    }
    // Stage this block's 24 q-rows (contiguous, coalesced)
    for (int i = t; i < ROWS_PER_BLOCK * E_DIM; i += 512)
        qs[i] = q[((size_t)bh * L_IN + chunk * ROWS_PER_BLOCK) * E_DIM + i];
    __syncthreads();

    float* wscratch = &scratch[w * 64];

    for (int j = 0; j < FI_PER; ++j) {
        const int lrow = w * FI_PER + j;      // [0, 24)
        const int l    = chunk * ROWS_PER_BLOCK + lrow;
        const int fi   = l >> 3;
        const int vi   = l & 7;

        // ---- dot phase: lane k<48 -> T[k]; lanes 48..55 -> V[k-48] ----
        int r;
        if (lane < 48) {
            r = (lane <= fi) ? (fi - lane) : (F_DIM + lane - fi);
        } else {
            int vj = (lane - 48) & 7;         // clamp lanes 56..63 to valid rows
            r = 96 + vi * 8 + vj;
        }
        const f32x4* qv = (const f32x4*)&qs[lrow * E_DIM];
        const f32x4* tv = (const f32x4*)&tabs[r * TSTRIDE];
        f32x4 acc = qv[0] * tv[0] + qv[1] * tv[1] + qv[2] * tv[2] + qv[3] * tv[3];
        const float s = acc.x + acc.y + acc.z + acc.w;
        if (lane < 56) wscratch[lane] = s;
        // Same-wave LDS pipe is in-order; fence stops compiler reordering.
        asm volatile("s_waitcnt lgkmcnt(0)" ::: "memory");
        __builtin_amdgcn_wave_barrier();

        // ---- write phase: 96 float4 (384 floats), lanes cover 64 + 32 ----
        float* orow = out + ((size_t)bh * L_IN + l) * L_OUT;
        #pragma unroll
        for (int rr = 0; rr < 2; ++rr) {
            const int jj = rr * 64 + lane;    // vec4 index [0, 96)
            if (jj < 96) {
                const float tval = wscratch[jj >> 1];           // T[m>>3], m=4*jj
                const f32x4 vv = *(const f32x4*)&wscratch[48 + 4 * (jj & 1)]; // V[m&7 ..]
                f32x4 o;
                o.x = tval + vv.x; o.y = tval + vv.y;
                o.z = tval + vv.z; o.w = tval + vv.w;
                __builtin_nontemporal_store(o, (f32x4*)(orow + 4 * jj));
            }
        }
        __builtin_amdgcn_wave_barrier();
    }
}

extern "C" void kernel_launch(void* const* d_in, const int* in_sizes, int n_in,
                              void* d_out, int out_size, void* d_ws, size_t ws_size,
                              hipStream_t stream) {
    const float* q        = (const float*)d_in[0];
    // d_in[1] = flipped_masks (unused)
    const float* r_voice  = (const float*)d_in[2];
    const float* e_past   = (const float*)d_in[3];
    const float* e_future = (const float*)d_in[4];
    float* out = (float*)d_out;

    dim3 grid(NCHUNK, SZ_B * H_DIM);  // (16, 32) = 512 blocks, 2/CU
    bsa_fused_kernel<<<grid, dim3(512), 0, stream>>>(q, r_voice, e_past, e_future, out);
}

// Round 12
// 11.215 us; speedup vs baseline: 1.3851x; 1.0339x over previous
//
#include <hip/hip_runtime.h>
#include <hip/hip_bf16.h>

// Constants from the reference
#define E_DIM 16
#define H_DIM 8
#define F_DIM 48
#define L_IN 384
#define L_OUT 384
#define SZ_B 4

#define NCHUNK 8            // l-chunks per bh (48 rows each)
#define ROWS_PER_BLOCK 48
#define ROWS_PER_WAVE 6
#define TSTRIDE 20          // padded table row stride (floats): 80 B, 16B-aligned b128 rows

typedef float f32x4 __attribute__((ext_vector_type(4)));

// R6 skeleton (10.67 us) + two trims:
//  (1) staging predicated to reachable table rows (chunk c uses fi in [6c,6c+5]
//      -> past[0..6c+5], future[1..47-6c] only): -27% gather traffic.
//  (2) batched dots -> ONE lgkmcnt fence -> stores packed into 9 fully-active
//      wave instructions (576 vec4 = 9 x 64) instead of 12 at 75% efficiency.
__global__ __launch_bounds__(512)
void bsa_fused_kernel(const float* __restrict__ q,
                      const float* __restrict__ r_voice,
                      const float* __restrict__ e_past,
                      const float* __restrict__ e_future,
                      float* __restrict__ out) {
    const int chunk = blockIdx.x;   // [0, 8)
    const int bh    = blockIdx.y;   // [0, 32)
    const int h     = bh & (H_DIM - 1);
    const int t     = threadIdx.x;  // [0, 512)
    const int w     = t >> 6;
    const int lane  = t & 63;

    const int fi_min = chunk * ROWS_PER_BLOCK / 8;        // 6*chunk
    const int fi_max = fi_min + 5;

    // Table rows (stride TSTRIDE): 0..47 past[diff], 48..95 future[diff], 96..159 voice
    __shared__ __attribute__((aligned(16))) float tabs[160 * TSTRIDE];        // 12.8 KB
    __shared__ __attribute__((aligned(16))) float qs[ROWS_PER_BLOCK * E_DIM]; // 3 KB
    __shared__ __attribute__((aligned(16))) float scratch[8][ROWS_PER_WAVE * 64]; // 12 KB

    // Stage transposed tables (one h-plane), predicated to reachable rows.
    for (int i = t; i < F_DIM * E_DIM; i += 512) {
        const int f = i >> 4, d = i & 15;
        if (f <= fi_max)                       // past diff in [0, fi_max]
            tabs[f * TSTRIDE + d] = e_past[(size_t)i * H_DIM + h];
        if (f >= 1 && f <= 47 - fi_min)        // future diff in [1, 47-fi_min]
            tabs[(F_DIM + f) * TSTRIDE + d] = e_future[(size_t)i * H_DIM + h];
    }
    for (int i = t; i < 64 * E_DIM; i += 512) {
        const int r = i >> 4, d = i & 15;
        tabs[(96 + r) * TSTRIDE + d] = r_voice[(size_t)i * H_DIM + h];
    }
    // Stage this block's 48 q-rows (contiguous, coalesced)
    for (int i = t; i < ROWS_PER_BLOCK * E_DIM; i += 512)
        qs[i] = q[((size_t)bh * L_IN + chunk * ROWS_PER_BLOCK) * E_DIM + i];
    __syncthreads();

    float* wscratch = scratch[w];
    const int lbase = chunk * ROWS_PER_BLOCK + w * ROWS_PER_WAVE;

    // ---- Phase A: 6 dot-rows back-to-back, no fences between ----
    #pragma unroll
    for (int j = 0; j < ROWS_PER_WAVE; ++j) {
        const int lrow = w * ROWS_PER_WAVE + j;   // [0, 48)
        const int l    = lbase + j;
        const int fi   = l >> 3;
        const int vi   = l & 7;
        int r;
        if (lane < 48) {
            r = (lane <= fi) ? (fi - lane) : (F_DIM + lane - fi);
        } else {
            r = 96 + vi * 8 + ((lane - 48) & 7);
        }
        const f32x4* qv = (const f32x4*)&qs[lrow * E_DIM];   // broadcast reads
        const f32x4* tv = (const f32x4*)&tabs[r * TSTRIDE];
        f32x4 acc = qv[0] * tv[0] + qv[1] * tv[1] + qv[2] * tv[2] + qv[3] * tv[3];
        const float s = acc.x + acc.y + acc.z + acc.w;
        if (lane < 56) wscratch[j * 64 + lane] = s;          // T[0..47], V[0..7]
    }
    // One fence for all scratch writes (wave-local; no block barrier).
    asm volatile("s_waitcnt lgkmcnt(0)" ::: "memory");
    __builtin_amdgcn_wave_barrier();

    // ---- Phase B: 576 vec4 over 9 fully-active wave store instructions ----
    float* obase = out + ((size_t)bh * L_IN + lbase) * L_OUT;
    #pragma unroll
    for (int it = 0; it < 9; ++it) {
        const int jj2 = it * 64 + lane;            // [0, 576)
        const int row = (jj2 * 683) >> 16;         // jj2 / 96 (exact for jj2<6144)
        const int jj  = jj2 - row * 96;            // [0, 96)
        const float* ws_ = &wscratch[row * 64];
        const float tval = ws_[jj >> 1];                         // T[m>>3]
        const f32x4 vv = *(const f32x4*)&ws_[48 + 4 * (jj & 1)]; // V[m&7..]
        f32x4 o;
        o.x = tval + vv.x; o.y = tval + vv.y;
        o.z = tval + vv.z; o.w = tval + vv.w;
        __builtin_nontemporal_store(o, (f32x4*)(obase + (size_t)row * L_OUT + 4 * jj));
    }
}

extern "C" void kernel_launch(void* const* d_in, const int* in_sizes, int n_in,
                              void* d_out, int out_size, void* d_ws, size_t ws_size,
                              hipStream_t stream) {
    const float* q        = (const float*)d_in[0];
    // d_in[1] = flipped_masks (unused)
    const float* r_voice  = (const float*)d_in[2];
    const float* e_past   = (const float*)d_in[3];
    const float* e_future = (const float*)d_in[4];
    float* out = (float*)d_out;

    dim3 grid(NCHUNK, SZ_B * H_DIM);  // (8, 32) = 256 blocks, 1/CU
    bsa_fused_kernel<<<grid, dim3(512), 0, stream>>>(q, r_voice, e_past, e_future, out);
}

// Round 13
// 10.898 us; speedup vs baseline: 1.4253x; 1.0290x over previous
//
#include <hip/hip_runtime.h>
#include <hip/hip_bf16.h>

// Constants from the reference
#define E_DIM 16
#define H_DIM 8
#define F_DIM 48
#define L_IN 384
#define L_OUT 384
#define SZ_B 4

#define NCHUNK 8            // fi-chunks per bh
#define ROWS_PER_BLOCK 48   // 6 fi * 8 vi
#define FI_PER 6
#define TSTRIDE 20          // padded table row stride (floats): 80 B, 16B-aligned b128 rows

typedef float f32x4 __attribute__((ext_vector_type(4)));

// FINAL: best-measured configuration (round 6, 10.67 us).
// out[bh, l, m] = sum_d q[bh,l,d] * ( r_voice[l%8, m%8, d, h] + rt(l/8, m/8, d, h) )
//   rt(fp,fq,d,h) = fp>=fq ? e_past[fp-fq,d,h] : e_future[fq-fp,d,h]
// Block = (chunk, bh), 512 threads, 1 block/CU. Full tables staged once
// (fi-independent; indexed by |fi-fq| at dot time). Wave w owns rows w*6..w*6+5;
// per row: 56 LDS dots -> wave-local scratch -> fence -> NT float4 stores.
// Cost model (established R7-R12): ~5 us fixed dispatch overhead + ~3 us HBM
// write floor + ~2.7 us staging/dots (latency-hidden across 8 waves). All
// single-variable perturbations (plain stores, scalar-q, batched fences,
// 2 blocks/CU, kernel split, predicated staging, packed stores) regressed.
__global__ __launch_bounds__(512)
void bsa_fused_kernel(const float* __restrict__ q,
                      const float* __restrict__ r_voice,
                      const float* __restrict__ e_past,
                      const float* __restrict__ e_future,
                      float* __restrict__ out) {
    const int chunk = blockIdx.x;   // [0, 8)
    const int bh    = blockIdx.y;   // [0, 32)
    const int h     = bh & (H_DIM - 1);
    const int t     = threadIdx.x;  // [0, 512)
    const int w     = t >> 6;
    const int lane  = t & 63;

    // Table rows (stride TSTRIDE): 0..47 past[diff], 48..95 future[diff], 96..159 voice
    __shared__ __attribute__((aligned(16))) float tabs[160 * TSTRIDE];  // 12.8 KB
    __shared__ __attribute__((aligned(16))) float qs[ROWS_PER_BLOCK * E_DIM]; // 3 KB
    __shared__ __attribute__((aligned(16))) float scratch[8 * 64];      // per-wave row results

    // Stage transposed tables (one h-plane). i = f*16+d; flat src = i*8+h.
    for (int i = t; i < F_DIM * E_DIM; i += 512) {
        const int f = i >> 4, d = i & 15;
        tabs[f * TSTRIDE + d]           = e_past [(size_t)i * H_DIM + h];
        tabs[(F_DIM + f) * TSTRIDE + d] = e_future[(size_t)i * H_DIM + h];
    }
    for (int i = t; i < 64 * E_DIM; i += 512) {
        const int r = i >> 4, d = i & 15;
        tabs[(96 + r) * TSTRIDE + d] = r_voice[(size_t)i * H_DIM + h];
    }
    // Stage this block's 48 q-rows (contiguous, coalesced)
    for (int i = t; i < ROWS_PER_BLOCK * E_DIM; i += 512)
        qs[i] = q[((size_t)bh * L_IN + chunk * ROWS_PER_BLOCK) * E_DIM + i];
    __syncthreads();

    float* wscratch = &scratch[w * 64];

    for (int j = 0; j < FI_PER; ++j) {
        const int lrow = w * FI_PER + j;      // [0, 48)
        const int l    = chunk * ROWS_PER_BLOCK + lrow;
        const int fi   = l >> 3;
        const int vi   = l & 7;

        // ---- dot phase: lane k<48 -> T[k]; lanes 48..55 -> V[k-48] ----
        int r;
        if (lane < 48) {
            r = (lane <= fi) ? (fi - lane) : (F_DIM + lane - fi);
        } else {
            int vj = (lane - 48) & 7;         // clamp lanes 56..63 to valid rows
            r = 96 + vi * 8 + vj;
        }
        const f32x4* qv = (const f32x4*)&qs[lrow * E_DIM];
        const f32x4* tv = (const f32x4*)&tabs[r * TSTRIDE];
        f32x4 acc = qv[0] * tv[0] + qv[1] * tv[1] + qv[2] * tv[2] + qv[3] * tv[3];
        const float s = acc.x + acc.y + acc.z + acc.w;
        if (lane < 56) wscratch[lane] = s;
        // Same-wave LDS pipe is in-order; fence stops compiler reordering.
        asm volatile("s_waitcnt lgkmcnt(0)" ::: "memory");
        __builtin_amdgcn_wave_barrier();

        // ---- write phase: 96 float4 (384 floats), lanes cover 64 + 32 ----
        float* orow = out + ((size_t)bh * L_IN + l) * L_OUT;
        #pragma unroll
        for (int rr = 0; rr < 2; ++rr) {
            const int jj = rr * 64 + lane;    // vec4 index [0, 96)
            if (jj < 96) {
                const float tval = wscratch[jj >> 1];           // T[m>>3], m=4*jj
                const f32x4 vv = *(const f32x4*)&wscratch[48 + 4 * (jj & 1)]; // V[m&7 ..]
                f32x4 o;
                o.x = tval + vv.x; o.y = tval + vv.y;
                o.z = tval + vv.z; o.w = tval + vv.w;
                __builtin_nontemporal_store(o, (f32x4*)(orow + 4 * jj));
            }
        }
        __builtin_amdgcn_wave_barrier();
    }
}

extern "C" void kernel_launch(void* const* d_in, const int* in_sizes, int n_in,
                              void* d_out, int out_size, void* d_ws, size_t ws_size,
                              hipStream_t stream) {
    const float* q        = (const float*)d_in[0];
    // d_in[1] = flipped_masks (unused)
    const float* r_voice  = (const float*)d_in[2];
    const float* e_past   = (const float*)d_in[3];
    const float* e_future = (const float*)d_in[4];
    float* out = (float*)d_out;

    dim3 grid(NCHUNK, SZ_B * H_DIM);  // (8, 32) = 256 blocks
    bsa_fused_kernel<<<grid, dim3(512), 0, stream>>>(q, r_voice, e_past, e_future, out);
}